// Round 15
// baseline (16943.359 us; speedup 1.0000x reference)
//
#include <hip/hip_runtime.h>
#include <hip/hip_bf16.h>

typedef __attribute__((ext_vector_type(8))) _Float16 half8;
typedef __attribute__((ext_vector_type(4))) float f32x4;
typedef __attribute__((ext_vector_type(4))) unsigned int uint4v;

#define MFMA_F16(a,b,c) __builtin_amdgcn_mfma_f32_16x16x32_f16((a),(b),(c),0,0,0)

namespace {
constexpr int kNS = 256, kNA = 8, kNI = 256, kNH = 512;
constexpr size_t kOutElems = (size_t)64*kNS*kNA*kNH;  // 33,554,432
constexpr float kScale = 2048.0f;
constexpr float kInv   = 1.0f/2048.0f;
constexpr int kWihHi = 0;
constexpr int kWihLo = 24576;
constexpr int kWhhHi = 49152;
constexpr int kWhhLo = 98304;
constexpr int kSmem  = 147456;
constexpr size_t kHPhase = 262144;
}

__device__ unsigned int g_hpk[2*kHPhase];
__device__ unsigned int g_cnt[512];
__device__ int          g_mode;

__device__ __forceinline__ float sigmoid_f(float v) { return 1.0f/(1.0f + __expf(-v)); }
__device__ __forceinline__ float tanh_f(float v) {
    float e = __expf(2.0f*v);
    return 1.0f - 2.0f/(e + 1.0f);
}
__device__ __forceinline__ void split2(float v, unsigned short& hi, unsigned short& lo) {
    _Float16 h = (_Float16)v;
    _Float16 l = (_Float16)((v - (float)h) * kScale);
    hi = __builtin_bit_cast(unsigned short, h);
    lo = __builtin_bit_cast(unsigned short, l);
}

__global__ void gru_prep(const unsigned int* __restrict__ is_init_raw) {
    for (int i = threadIdx.x; i < 512; i += 256)
        __hip_atomic_store(&g_cnt[i], 0u, __ATOMIC_RELAXED, __HIP_MEMORY_SCOPE_AGENT);
    if (threadIdx.x == 0) g_mode = 0;
    __syncthreads();
    unsigned m = 0;
    for (int i = threadIdx.x; i < 4096; i += 256) {
        unsigned v = is_init_raw[i];
        if (v == 0x00003F80u || v == 0x3F803F80u) m |= 4u;
        else if (v == 0x3F800000u)                m |= 2u;
        else if (v > 1u)                          m |= 1u;
    }
    if (m) atomicOr(&g_mode, (int)m);
}

// ABLATION (R15): V0 FULL | V1 NOSPIN | V2 NOEXCH | V3 NOGI | V4 FLOOR
// Per-dispatch dur_us from rocprof isolates: spin(V0-V1), h-loads(V0-V2),
// gi(V0-V3), all-sync(V0-V4). V0 runs LAST -> d_out correct.
template<int V>
__global__ void __launch_bounds__(256, 1)
gru_main(const float* __restrict__ x, const void* __restrict__ is_init,
         const float* __restrict__ w_ih, const float* __restrict__ w_hh,
         const float* __restrict__ b_ih, const float* __restrict__ b_hh,
         float* __restrict__ out)
{
    constexpr bool DO_SPIN = (V==0 || V==2 || V==3);
    constexpr bool DO_PUB  = (V!=4);
    constexpr bool DO_EXCH = (V==0 || V==1);
    constexpr bool DO_GI   = (V!=3);

    extern __shared__ char smem[];
    const int tid = threadIdx.x;
    const int bx  = blockIdx.x;
    const int mi  = bx & 7;
    const int ci  = bx >> 3;
    const int c0  = ci * 16;

    for (int idx = tid; idx < 3072; idx += 256) {
        int jr = idx >> 6, q = idx & 63;
        int j = (jr >> 4)*kNH + c0 + (jr & 15);
        float4 v = *(const float4*)(w_ih + (size_t)j*kNI + q*4);
        ushort4 hi, lo;
        split2(v.x, hi.x, lo.x); split2(v.y, hi.y, lo.y);
        split2(v.z, hi.z, lo.z); split2(v.w, hi.w, lo.w);
        unsigned off = ((unsigned)(jr*512 + q*8)) ^ ((unsigned)(jr & 7) << 4);
        *(ushort4*)(smem + kWihHi + off) = hi;
        *(ushort4*)(smem + kWihLo + off) = lo;
    }
    for (int idx = tid; idx < 6144; idx += 256) {
        int jr = idx >> 7, q = idx & 127;
        int j = (jr >> 4)*kNH + c0 + (jr & 15);
        float4 v = *(const float4*)(w_hh + (size_t)j*kNH + q*4);
        ushort4 hi, lo;
        split2(v.x, hi.x, lo.x); split2(v.y, hi.y, lo.y);
        split2(v.z, hi.z, lo.z); split2(v.w, hi.w, lo.w);
        unsigned off = ((unsigned)(jr*1024 + q*8)) ^ ((unsigned)(jr & 7) << 4);
        *(ushort4*)(smem + kWhhHi + off) = hi;
        *(ushort4*)(smem + kWhhLo + off) = lo;
    }
    __syncthreads();

    const int fm = g_mode;
    const int fmode = (fm & 4) ? 3 : (fm & 2) ? 2 : (fm & 1) ? 1 : 0;

    const int l    = tid & 63, w = tid >> 6;
    const int lrow = l & 15, kgrp = l >> 4;

    const int cE = c0 + lrow;
    const int mA = mi*64 + w*16 + lrow;
    const int bA = mA >> 3;
    const size_t xrow0 = ((size_t)bA*(kNS*kNA) + (mA & 7))*kNI + kgrp*8;

    const unsigned swzb = (unsigned)(lrow & 7) << 4;
    unsigned wihB[3], whhB[3];
    #pragma unroll
    for (int g = 0; g < 3; ++g) {
        wihB[g] = (unsigned)((g*16 + lrow)*512  + kgrp*16);
        whhB[g] = (unsigned)((g*16 + lrow)*1024 + kgrp*16);
    }

    const float biasR  = b_ih[cE]        + b_hh[cE];
    const float biasZ  = b_ih[kNH + cE]  + b_hh[kNH + cE];
    const float biasIN = b_ih[2*kNH + cE];
    const float biasHN = b_hh[2*kNH + cE];
    const int mE0 = mi*64 + w*16 + kgrp*4;
    const int bE  = mE0 >> 3, aE0 = mE0 & 7;

    unsigned int* cnt = &g_cnt[mi*64];
    float hreg[4] = {0.f, 0.f, 0.f, 0.f};
    float* hn_out = out + kOutElems;
    int dead = 0;

#define LOADX(dh, dl, ss) do {                                                     \
        const float* xr_ = x + xrow0 + (size_t)(ss)*(kNA*kNI);                     \
        _Pragma("unroll")                                                          \
        for (int kb_ = 0; kb_ < 8; ++kb_) {                                        \
            float4 v0_ = *(const float4*)(xr_ + kb_*32);                           \
            float4 v1_ = *(const float4*)(xr_ + kb_*32 + 4);                       \
            float vv_[8] = {v0_.x,v0_.y,v0_.z,v0_.w,v1_.x,v1_.y,v1_.z,v1_.w};      \
            half8 th_, tl_;                                                        \
            _Pragma("unroll")                                                      \
            for (int e_ = 0; e_ < 8; ++e_) {                                       \
                _Float16 h_ = (_Float16)vv_[e_];                                   \
                th_[e_] = h_;                                                      \
                tl_[e_] = (_Float16)((vv_[e_] - (float)h_) * kScale);              \
            }                                                                      \
            dh[kb_] = th_; dl[kb_] = tl_;                                          \
        }                                                                          \
    } while (0)

    half8 xfh[8], xfl[8], xnh[8], xnl[8];
    if (DO_GI) LOADX(xfh, xfl, 0);

    for (int s = 0; s < kNS; ++s) {
        const int ii = bA*kNS + s;
        const int ie = bE*kNS + s;
        int iniA, iniE;
        switch (fmode) {
            case 3:  iniA = ((const unsigned short*)is_init)[ii] != 0;
                     iniE = ((const unsigned short*)is_init)[ie] != 0; break;
            case 2:  iniA = ((const float*)is_init)[ii] != 0.f;
                     iniE = ((const float*)is_init)[ie] != 0.f;       break;
            case 1:  iniA = ((const unsigned char*)is_init)[ii] != 0;
                     iniE = ((const unsigned char*)is_init)[ie] != 0; break;
            default: iniA = ((const int*)is_init)[ii] != 0;
                     iniE = ((const int*)is_init)[ie] != 0;           break;
        }
        f32x4 aR = {0,0,0,0}, aZ = {0,0,0,0}, aGN = {0,0,0,0}, aHN = {0,0,0,0};
        f32x4 lR = {0,0,0,0}, lZ = {0,0,0,0}, lGN = {0,0,0,0}, lHN = {0,0,0,0};

        if (DO_GI) {
            #pragma unroll
            for (int kb = 0; kb < 8; ++kb) {
                {   half8 bhi = *(const half8*)(smem + kWihHi + ((wihB[0] + kb*64) ^ swzb));
                    half8 blo = *(const half8*)(smem + kWihLo + ((wihB[0] + kb*64) ^ swzb));
                    aR = MFMA_F16(xfh[kb], bhi, aR);
                    lR = MFMA_F16(xfl[kb], bhi, lR);
                    lR = MFMA_F16(xfh[kb], blo, lR); }
                {   half8 bhi = *(const half8*)(smem + kWihHi + ((wihB[1] + kb*64) ^ swzb));
                    half8 blo = *(const half8*)(smem + kWihLo + ((wihB[1] + kb*64) ^ swzb));
                    aZ = MFMA_F16(xfh[kb], bhi, aZ);
                    lZ = MFMA_F16(xfl[kb], bhi, lZ);
                    lZ = MFMA_F16(xfh[kb], blo, lZ); }
                {   half8 bhi = *(const half8*)(smem + kWihHi + ((wihB[2] + kb*64) ^ swzb));
                    half8 blo = *(const half8*)(smem + kWihLo + ((wihB[2] + kb*64) ^ swzb));
                    aGN = MFMA_F16(xfh[kb], bhi, aGN);
                    lGN = MFMA_F16(xfl[kb], bhi, lGN);
                    lGN = MFMA_F16(xfh[kb], blo, lGN); }
            }
            if (s + 1 < kNS) LOADX(xnh, xnl, s + 1);
        }

        if (s > 0) {
            if (DO_SPIN) {
                if (tid == 0 && !dead) {
                    const unsigned target = (unsigned)(32*s);
                    long it = 0;
                    while (__hip_atomic_load(cnt, __ATOMIC_RELAXED, __HIP_MEMORY_SCOPE_AGENT) < target) {
                        if (++it > 50000000L) { dead = 1; break; }
                        __builtin_amdgcn_s_sleep(1);
                    }
                }
            }
            __syncthreads();
            const unsigned int* hp = g_hpk + (size_t)(s & 1)*kHPhase + (size_t)mA*kNH + kgrp*8;
            const half8 zz = {};
            #pragma unroll
            for (int kb = 0; kb < 16; ++kb) {
                half8 ahi, alo;
                if (DO_EXCH) {
                    unsigned wv[8];
                    #pragma unroll
                    for (int e = 0; e < 8; ++e)
                        wv[e] = __hip_atomic_load(hp + kb*32 + e, __ATOMIC_RELAXED,
                                                  __HIP_MEMORY_SCOPE_AGENT);
                    uint4v ph, pl;
                    ph[0] = (wv[0]&0xFFFFu)|(wv[1]<<16); pl[0] = (wv[0]>>16)|(wv[1]&0xFFFF0000u);
                    ph[1] = (wv[2]&0xFFFFu)|(wv[3]<<16); pl[1] = (wv[2]>>16)|(wv[3]&0xFFFF0000u);
                    ph[2] = (wv[4]&0xFFFFu)|(wv[5]<<16); pl[2] = (wv[4]>>16)|(wv[5]&0xFFFF0000u);
                    ph[3] = (wv[6]&0xFFFFu)|(wv[7]<<16); pl[3] = (wv[6]>>16)|(wv[7]&0xFFFF0000u);
                    ahi = __builtin_bit_cast(half8, ph);
                    alo = __builtin_bit_cast(half8, pl);
                    ahi = iniA ? zz : ahi;
                    alo = iniA ? zz : alo;
                } else {
                    ahi = zz; alo = zz;
                }
                {   half8 bhi = *(const half8*)(smem + kWhhHi + ((whhB[0] + kb*64) ^ swzb));
                    half8 blo = *(const half8*)(smem + kWhhLo + ((whhB[0] + kb*64) ^ swzb));
                    aR = MFMA_F16(ahi, bhi, aR);
                    lR = MFMA_F16(alo, bhi, lR);
                    lR = MFMA_F16(ahi, blo, lR); }
                {   half8 bhi = *(const half8*)(smem + kWhhHi + ((whhB[1] + kb*64) ^ swzb));
                    half8 blo = *(const half8*)(smem + kWhhLo + ((whhB[1] + kb*64) ^ swzb));
                    aZ = MFMA_F16(ahi, bhi, aZ);
                    lZ = MFMA_F16(alo, bhi, lZ);
                    lZ = MFMA_F16(ahi, blo, lZ); }
                {   half8 bhi = *(const half8*)(smem + kWhhHi + ((whhB[2] + kb*64) ^ swzb));
                    half8 blo = *(const half8*)(smem + kWhhLo + ((whhB[2] + kb*64) ^ swzb));
                    aHN = MFMA_F16(ahi, bhi, aHN);
                    lHN = MFMA_F16(alo, bhi, lHN);
                    lHN = MFMA_F16(ahi, blo, lHN); }
            }
        }

        unsigned int* hop = g_hpk + (size_t)((s+1) & 1)*kHPhase;
        const size_t obase = ((size_t)bE*(kNS*kNA) + (size_t)s*kNA + aE0)*kNH + cE;
        #pragma unroll
        for (int i = 0; i < 4; ++i) {
            float pr  = aR[i]  + lR[i]*kInv  + biasR;
            float pz  = aZ[i]  + lZ[i]*kInv  + biasZ;
            float gin = aGN[i] + lGN[i]*kInv + biasIN;
            float ghn = aHN[i] + lHN[i]*kInv + biasHN;
            float htv = iniE ? 0.f : hreg[i];
            float r  = sigmoid_f(pr);
            float zg = sigmoid_f(pz);
            float nn = tanh_f(gin + r*ghn);
            float hv = (1.f - zg)*nn + zg*htv;
            hreg[i] = hv;
            out[obase + (size_t)i*kNH] = hv;
            unsigned short shi, slo;
            split2(hv, shi, slo);
            unsigned int pk = (unsigned)shi | ((unsigned)slo << 16);
            __hip_atomic_store(&hop[(size_t)(mE0 + i)*kNH + cE], pk,
                               __ATOMIC_RELAXED, __HIP_MEMORY_SCOPE_AGENT);
        }
        if (s == kNS-1) {
            #pragma unroll
            for (int i = 0; i < 4; ++i)
                hn_out[(size_t)(mE0 + i)*kNH + cE] = hreg[i];
        }

        if (s < kNS-1) {
            __syncthreads();
            if (DO_PUB) {
                if (tid == 0)
                    __hip_atomic_fetch_add(cnt, 1u, __ATOMIC_RELAXED, __HIP_MEMORY_SCOPE_AGENT);
            }
            if (DO_GI) {
                #pragma unroll
                for (int i = 0; i < 8; ++i) { xfh[i] = xnh[i]; xfl[i] = xnl[i]; }
            }
        }
    }
#undef LOADX
}

extern "C" void kernel_launch(void* const* d_in, const int* in_sizes, int n_in,
                              void* d_out, int out_size, void* d_ws, size_t ws_size,
                              hipStream_t stream) {
    const int want[6] = {33554432, 16384, 393216, 786432, 1536, 1536};
    const void* res[6] = {nullptr, nullptr, nullptr, nullptr, nullptr, nullptr};
    bool used[64] = {false};
    for (int k = 0; k < 6; ++k)
        for (int i = 0; i < n_in && i < 64; ++i)
            if (!used[i] && in_sizes[i] == want[k]) { res[k] = d_in[i]; used[i] = true; break; }
    bool ok = true;
    for (int k = 0; k < 6; ++k) if (!res[k]) ok = false;
    if (!ok) for (int k = 0; k < 6; ++k) res[k] = d_in[k];

    const float* x       = (const float*)res[0];
    const void*  is_init = res[1];
    const float* w_ih    = (const float*)res[2];
    const float* w_hh    = (const float*)res[3];
    const float* b_ih    = (const float*)res[4];
    const float* b_hh    = (const float*)res[5];
    float* out = (float*)d_out;

    hipFuncSetAttribute((const void*)gru_main<0>, hipFuncAttributeMaxDynamicSharedMemorySize, kSmem);
    hipFuncSetAttribute((const void*)gru_main<1>, hipFuncAttributeMaxDynamicSharedMemorySize, kSmem);
    hipFuncSetAttribute((const void*)gru_main<2>, hipFuncAttributeMaxDynamicSharedMemorySize, kSmem);
    hipFuncSetAttribute((const void*)gru_main<3>, hipFuncAttributeMaxDynamicSharedMemorySize, kSmem);
    hipFuncSetAttribute((const void*)gru_main<4>, hipFuncAttributeMaxDynamicSharedMemorySize, kSmem);

    // Ablation sequence; V0 (FULL) last -> final out deterministic + correct.
    gru_prep<<<1, 256, 0, stream>>>((const unsigned int*)is_init);
    gru_main<1><<<256, 256, kSmem, stream>>>(x, is_init, w_ih, w_hh, b_ih, b_hh, out);
    gru_prep<<<1, 256, 0, stream>>>((const unsigned int*)is_init);
    gru_main<2><<<256, 256, kSmem, stream>>>(x, is_init, w_ih, w_hh, b_ih, b_hh, out);
    gru_prep<<<1, 256, 0, stream>>>((const unsigned int*)is_init);
    gru_main<3><<<256, 256, kSmem, stream>>>(x, is_init, w_ih, w_hh, b_ih, b_hh, out);
    gru_prep<<<1, 256, 0, stream>>>((const unsigned int*)is_init);
    gru_main<4><<<256, 256, kSmem, stream>>>(x, is_init, w_ih, w_hh, b_ih, b_hh, out);
    gru_prep<<<1, 256, 0, stream>>>((const unsigned int*)is_init);
    gru_main<0><<<256, 256, kSmem, stream>>>(x, is_init, w_ih, w_hh, b_ih, b_hh, out);
}

// Round 16
// 6282.856 us; speedup vs baseline: 2.6968x; 2.6968x over previous
//
#include <hip/hip_runtime.h>
#include <hip/hip_bf16.h>

typedef __attribute__((ext_vector_type(8))) _Float16 half8;
typedef __attribute__((ext_vector_type(4))) float f32x4;
typedef __attribute__((ext_vector_type(4))) unsigned int uint4v;

#define MFMA_F16(a,b,c) __builtin_amdgcn_mfma_f32_16x16x32_f16((a),(b),(c),0,0,0)

namespace {
constexpr int kNS = 256, kNA = 8, kNI = 256, kNH = 512;
constexpr size_t kOutElems = (size_t)64*kNS*kNA*kNH;  // 33,554,432
constexpr float kScale = 2048.0f;
constexpr float kInv   = 1.0f/2048.0f;
constexpr int kWihHi = 0;
constexpr int kWihLo = 24576;
constexpr int kWhhHi = 49152;
constexpr int kWhhLo = 98304;
constexpr int kSmem  = 147456;     // 147 KB -> 1 wg/CU
constexpr size_t kHPhase = 262144; // u32 elements per phase (512x512)
}

// h exchanged as PACKED u32 via agent-scope RELAXED atomics (L3-coherent).
// Sync: per-wg STEP-STAMPED flags (no RMW hotspot — R15 ablation: the shared
// fetch_add counter serialized 32 RMWs/step ≈ 4.4 ms of the 5.9 ms total).
__device__ unsigned int g_hpk[2*kHPhase];   // 2 MB
__device__ unsigned int g_flag[4096];       // 256 wgs x 16-dword stride (64 B)
__device__ int          g_mode;             // is_init dtype

__device__ __forceinline__ float sigmoid_f(float v) { return 1.0f/(1.0f + __expf(-v)); }
__device__ __forceinline__ float tanh_f(float v) {
    float e = __expf(2.0f*v);
    return 1.0f - 2.0f/(e + 1.0f);
}
__device__ __forceinline__ void split2(float v, unsigned short& hi, unsigned short& lo) {
    _Float16 h = (_Float16)v;
    _Float16 l = (_Float16)((v - (float)h) * kScale);
    hi = __builtin_bit_cast(unsigned short, h);
    lo = __builtin_bit_cast(unsigned short, l);
}

// Prep (1 block): zero flags via agent atomics; detect is_init dtype (4-way).
__global__ void gru_prep(const unsigned int* __restrict__ is_init_raw) {
    for (int i = threadIdx.x; i < 4096; i += 256)
        __hip_atomic_store(&g_flag[i], 0u, __ATOMIC_RELAXED, __HIP_MEMORY_SCOPE_AGENT);
    if (threadIdx.x == 0) g_mode = 0;
    __syncthreads();
    unsigned m = 0;
    for (int i = threadIdx.x; i < 4096; i += 256) {
        unsigned v = is_init_raw[i];
        if (v == 0x00003F80u || v == 0x3F803F80u) m |= 4u;
        else if (v == 0x3F800000u)                m |= 2u;
        else if (v > 1u)                          m |= 1u;
    }
    if (m) atomicOr(&g_mode, (int)m);
}

// Persistent GRU. 256 wgs x 256 thr; 1 wg/CU. mi = bx&7 (8 groups x 64 rows,
// 32 wgs/group), ci = bx>>3 (32 col-blocks x 16). Split-fp16 MFMA, fp32 h.
__global__ void __launch_bounds__(256, 1)
gru_main(const float* __restrict__ x, const void* __restrict__ is_init,
         const float* __restrict__ w_ih, const float* __restrict__ w_hh,
         const float* __restrict__ b_ih, const float* __restrict__ b_hh,
         float* __restrict__ out)
{
    extern __shared__ char smem[];
    const int tid = threadIdx.x;
    const int bx  = blockIdx.x;
    const int mi  = bx & 7;
    const int ci  = bx >> 3;
    const int c0  = ci * 16;

    for (int idx = tid; idx < 3072; idx += 256) {           // w_ih: 48 x 64 float4
        int jr = idx >> 6, q = idx & 63;
        int j = (jr >> 4)*kNH + c0 + (jr & 15);
        float4 v = *(const float4*)(w_ih + (size_t)j*kNI + q*4);
        ushort4 hi, lo;
        split2(v.x, hi.x, lo.x); split2(v.y, hi.y, lo.y);
        split2(v.z, hi.z, lo.z); split2(v.w, hi.w, lo.w);
        unsigned off = ((unsigned)(jr*512 + q*8)) ^ ((unsigned)(jr & 7) << 4);
        *(ushort4*)(smem + kWihHi + off) = hi;
        *(ushort4*)(smem + kWihLo + off) = lo;
    }
    for (int idx = tid; idx < 6144; idx += 256) {           // w_hh: 48 x 128 float4
        int jr = idx >> 7, q = idx & 127;
        int j = (jr >> 4)*kNH + c0 + (jr & 15);
        float4 v = *(const float4*)(w_hh + (size_t)j*kNH + q*4);
        ushort4 hi, lo;
        split2(v.x, hi.x, lo.x); split2(v.y, hi.y, lo.y);
        split2(v.z, hi.z, lo.z); split2(v.w, hi.w, lo.w);
        unsigned off = ((unsigned)(jr*1024 + q*8)) ^ ((unsigned)(jr & 7) << 4);
        *(ushort4*)(smem + kWhhHi + off) = hi;
        *(ushort4*)(smem + kWhhLo + off) = lo;
    }
    __syncthreads();

    const int fm = g_mode;
    const int fmode = (fm & 4) ? 3 : (fm & 2) ? 2 : (fm & 1) ? 1 : 0;

    const int l    = tid & 63, w = tid >> 6;
    const int lrow = l & 15, kgrp = l >> 4;

    const int cE = c0 + lrow;
    const int mA = mi*64 + w*16 + lrow;
    const int bA = mA >> 3;
    const size_t xrow0 = ((size_t)bA*(kNS*kNA) + (mA & 7))*kNI + kgrp*8;

    const unsigned swzb = (unsigned)(lrow & 7) << 4;
    unsigned wihB[3], whhB[3];
    #pragma unroll
    for (int g = 0; g < 3; ++g) {
        wihB[g] = (unsigned)((g*16 + lrow)*512  + kgrp*16);
        whhB[g] = (unsigned)((g*16 + lrow)*1024 + kgrp*16);
    }

    const float biasR  = b_ih[cE]        + b_hh[cE];
    const float biasZ  = b_ih[kNH + cE]  + b_hh[kNH + cE];
    const float biasIN = b_ih[2*kNH + cE];
    const float biasHN = b_hh[2*kNH + cE];
    const int mE0 = mi*64 + w*16 + kgrp*4;
    const int bE  = mE0 >> 3, aE0 = mE0 & 7;

    float hreg[4] = {0.f, 0.f, 0.f, 0.f};
    float* hn_out = out + kOutElems;
    int dead = 0;                      // per-lane latched bailout (tid<32)
    const unsigned myFlag  = (unsigned)((mi*32 + ci)*16);
    const unsigned grpFlag = (unsigned)(mi*32)*16;   // + lane*16 for tid<32

#define LOADX(dh, dl, ss) do {                                                     \
        const float* xr_ = x + xrow0 + (size_t)(ss)*(kNA*kNI);                     \
        _Pragma("unroll")                                                          \
        for (int kb_ = 0; kb_ < 8; ++kb_) {                                        \
            float4 v0_ = *(const float4*)(xr_ + kb_*32);                           \
            float4 v1_ = *(const float4*)(xr_ + kb_*32 + 4);                       \
            float vv_[8] = {v0_.x,v0_.y,v0_.z,v0_.w,v1_.x,v1_.y,v1_.z,v1_.w};      \
            half8 th_, tl_;                                                        \
            _Pragma("unroll")                                                      \
            for (int e_ = 0; e_ < 8; ++e_) {                                       \
                _Float16 h_ = (_Float16)vv_[e_];                                   \
                th_[e_] = h_;                                                      \
                tl_[e_] = (_Float16)((vv_[e_] - (float)h_) * kScale);              \
            }                                                                      \
            dh[kb_] = th_; dl[kb_] = tl_;                                          \
        }                                                                          \
    } while (0)

    half8 xfh[8], xfl[8], xnh[8], xnl[8];
    LOADX(xfh, xfl, 0);

    for (int s = 0; s < kNS; ++s) {
        const int ii = bA*kNS + s;
        const int ie = bE*kNS + s;
        int iniA, iniE;
        switch (fmode) {
            case 3:  iniA = ((const unsigned short*)is_init)[ii] != 0;
                     iniE = ((const unsigned short*)is_init)[ie] != 0; break;
            case 2:  iniA = ((const float*)is_init)[ii] != 0.f;
                     iniE = ((const float*)is_init)[ie] != 0.f;       break;
            case 1:  iniA = ((const unsigned char*)is_init)[ii] != 0;
                     iniE = ((const unsigned char*)is_init)[ie] != 0; break;
            default: iniA = ((const int*)is_init)[ii] != 0;
                     iniE = ((const int*)is_init)[ie] != 0;           break;
        }
        f32x4 aR = {0,0,0,0}, aZ = {0,0,0,0}, aGN = {0,0,0,0}, aHN = {0,0,0,0};
        f32x4 lR = {0,0,0,0}, lZ = {0,0,0,0}, lGN = {0,0,0,0}, lHN = {0,0,0,0};

        // ---- gi (independent of h; runs before the wait) ----
        #pragma unroll
        for (int kb = 0; kb < 8; ++kb) {
            {   half8 bhi = *(const half8*)(smem + kWihHi + ((wihB[0] + kb*64) ^ swzb));
                half8 blo = *(const half8*)(smem + kWihLo + ((wihB[0] + kb*64) ^ swzb));
                aR = MFMA_F16(xfh[kb], bhi, aR);
                lR = MFMA_F16(xfl[kb], bhi, lR);
                lR = MFMA_F16(xfh[kb], blo, lR); }
            {   half8 bhi = *(const half8*)(smem + kWihHi + ((wihB[1] + kb*64) ^ swzb));
                half8 blo = *(const half8*)(smem + kWihLo + ((wihB[1] + kb*64) ^ swzb));
                aZ = MFMA_F16(xfh[kb], bhi, aZ);
                lZ = MFMA_F16(xfl[kb], bhi, lZ);
                lZ = MFMA_F16(xfh[kb], blo, lZ); }
            {   half8 bhi = *(const half8*)(smem + kWihHi + ((wihB[2] + kb*64) ^ swzb));
                half8 blo = *(const half8*)(smem + kWihLo + ((wihB[2] + kb*64) ^ swzb));
                aGN = MFMA_F16(xfh[kb], bhi, aGN);
                lGN = MFMA_F16(xfl[kb], bhi, lGN);
                lGN = MFMA_F16(xfh[kb], blo, lGN); }
        }

        if (s + 1 < kNS) LOADX(xnh, xnl, s + 1);

        // ---- wait for h(s): 32 lanes poll 32 producer flags IN PARALLEL ----
        if (s > 0) {
            if (tid < 32 && !dead) {
                const unsigned target = (unsigned)s;
                long it = 0;
                while (__hip_atomic_load(&g_flag[grpFlag + tid*16], __ATOMIC_RELAXED,
                                         __HIP_MEMORY_SCOPE_AGENT) < target) {
                    if (++it > 50000000L) { dead = 1; break; }
                    __builtin_amdgcn_s_sleep(1);
                }
            }
            __syncthreads();
            const unsigned int* hp = g_hpk + (size_t)(s & 1)*kHPhase + (size_t)mA*kNH + kgrp*8;
            const half8 zz = {};
            #pragma unroll
            for (int kb = 0; kb < 16; ++kb) {
                unsigned wv[8];
                #pragma unroll
                for (int e = 0; e < 8; ++e)
                    wv[e] = __hip_atomic_load(hp + kb*32 + e, __ATOMIC_RELAXED,
                                              __HIP_MEMORY_SCOPE_AGENT);
                uint4v ph, pl;
                ph[0] = (wv[0]&0xFFFFu)|(wv[1]<<16); pl[0] = (wv[0]>>16)|(wv[1]&0xFFFF0000u);
                ph[1] = (wv[2]&0xFFFFu)|(wv[3]<<16); pl[1] = (wv[2]>>16)|(wv[3]&0xFFFF0000u);
                ph[2] = (wv[4]&0xFFFFu)|(wv[5]<<16); pl[2] = (wv[4]>>16)|(wv[5]&0xFFFF0000u);
                ph[3] = (wv[6]&0xFFFFu)|(wv[7]<<16); pl[3] = (wv[6]>>16)|(wv[7]&0xFFFF0000u);
                half8 ahi = __builtin_bit_cast(half8, ph);
                half8 alo = __builtin_bit_cast(half8, pl);
                ahi = iniA ? zz : ahi;
                alo = iniA ? zz : alo;
                {   half8 bhi = *(const half8*)(smem + kWhhHi + ((whhB[0] + kb*64) ^ swzb));
                    half8 blo = *(const half8*)(smem + kWhhLo + ((whhB[0] + kb*64) ^ swzb));
                    aR = MFMA_F16(ahi, bhi, aR);
                    lR = MFMA_F16(alo, bhi, lR);
                    lR = MFMA_F16(ahi, blo, lR); }
                {   half8 bhi = *(const half8*)(smem + kWhhHi + ((whhB[1] + kb*64) ^ swzb));
                    half8 blo = *(const half8*)(smem + kWhhLo + ((whhB[1] + kb*64) ^ swzb));
                    aZ = MFMA_F16(ahi, bhi, aZ);
                    lZ = MFMA_F16(alo, bhi, lZ);
                    lZ = MFMA_F16(ahi, blo, lZ); }
                {   half8 bhi = *(const half8*)(smem + kWhhHi + ((whhB[2] + kb*64) ^ swzb));
                    half8 blo = *(const half8*)(smem + kWhhLo + ((whhB[2] + kb*64) ^ swzb));
                    aHN = MFMA_F16(ahi, bhi, aHN);
                    lHN = MFMA_F16(alo, bhi, lHN);
                    lHN = MFMA_F16(ahi, blo, lHN); }
            }
        }

        // ---- gates + h update; h stores FIRST (critical path), out LATER ----
        unsigned int* hop = g_hpk + (size_t)((s+1) & 1)*kHPhase;
        float hvout[4];
        #pragma unroll
        for (int i = 0; i < 4; ++i) {
            float pr  = aR[i]  + lR[i]*kInv  + biasR;
            float pz  = aZ[i]  + lZ[i]*kInv  + biasZ;
            float gin = aGN[i] + lGN[i]*kInv + biasIN;
            float ghn = aHN[i] + lHN[i]*kInv + biasHN;
            float htv = iniE ? 0.f : hreg[i];
            float r  = sigmoid_f(pr);
            float zg = sigmoid_f(pz);
            float nn = tanh_f(gin + r*ghn);
            float hv = (1.f - zg)*nn + zg*htv;
            hreg[i] = hv; hvout[i] = hv;
            unsigned short shi, slo;
            split2(hv, shi, slo);
            unsigned int pk = (unsigned)shi | ((unsigned)slo << 16);
            __hip_atomic_store(&hop[(size_t)(mE0 + i)*kNH + cE], pk,
                               __ATOMIC_RELAXED, __HIP_MEMORY_SCOPE_AGENT);
        }

        // ---- publish h(s+1): per-wg step-stamp flag (plain store, no RMW) ----
        if (s < kNS-1) {
            __syncthreads();   // per-wave vmcnt(0): h stores acked at L3
            if (tid == 0)
                __hip_atomic_store(&g_flag[myFlag], (unsigned)(s+1),
                                   __ATOMIC_RELAXED, __HIP_MEMORY_SCOPE_AGENT);
        }

        // ---- out stores off the critical path (drain overlaps next step) ----
        const size_t obase = ((size_t)bE*(kNS*kNA) + (size_t)s*kNA + aE0)*kNH + cE;
        #pragma unroll
        for (int i = 0; i < 4; ++i)
            out[obase + (size_t)i*kNH] = hvout[i];
        if (s == kNS-1) {
            #pragma unroll
            for (int i = 0; i < 4; ++i)
                hn_out[(size_t)(mE0 + i)*kNH + cE] = hreg[i];
        }

        if (s < kNS-1) {
            #pragma unroll
            for (int i = 0; i < 8; ++i) { xfh[i] = xnh[i]; xfl[i] = xnl[i]; }
        }
    }
#undef LOADX
}

extern "C" void kernel_launch(void* const* d_in, const int* in_sizes, int n_in,
                              void* d_out, int out_size, void* d_ws, size_t ws_size,
                              hipStream_t stream) {
    const int want[6] = {33554432, 16384, 393216, 786432, 1536, 1536};
    const void* res[6] = {nullptr, nullptr, nullptr, nullptr, nullptr, nullptr};
    bool used[64] = {false};
    for (int k = 0; k < 6; ++k)
        for (int i = 0; i < n_in && i < 64; ++i)
            if (!used[i] && in_sizes[i] == want[k]) { res[k] = d_in[i]; used[i] = true; break; }
    bool ok = true;
    for (int k = 0; k < 6; ++k) if (!res[k]) ok = false;
    if (!ok) for (int k = 0; k < 6; ++k) res[k] = d_in[k];

    const float* x       = (const float*)res[0];
    const void*  is_init = res[1];
    const float* w_ih    = (const float*)res[2];
    const float* w_hh    = (const float*)res[3];
    const float* b_ih    = (const float*)res[4];
    const float* b_hh    = (const float*)res[5];
    float* out = (float*)d_out;

    gru_prep<<<1, 256, 0, stream>>>((const unsigned int*)is_init);

    hipFuncSetAttribute((const void*)gru_main,
                        hipFuncAttributeMaxDynamicSharedMemorySize, kSmem);
    gru_main<<<256, 256, kSmem, stream>>>(x, is_init, w_ih, w_hh, b_ih, b_hh, out);
}

// Round 17
// 3699.611 us; speedup vs baseline: 4.5798x; 1.6982x over previous
//
#include <hip/hip_runtime.h>
#include <hip/hip_bf16.h>

typedef __attribute__((ext_vector_type(8))) _Float16 half8;
typedef __attribute__((ext_vector_type(4))) float f32x4;
typedef __attribute__((ext_vector_type(4))) unsigned int uint4v;

#define MFMA_F16(a,b,c) __builtin_amdgcn_mfma_f32_16x16x32_f16((a),(b),(c),0,0,0)

namespace {
constexpr int kNS = 256, kNA = 8, kNI = 256, kNH = 512;
constexpr size_t kOutElems = (size_t)64*kNS*kNA*kNH;  // 33,554,432
constexpr float kScale = 2048.0f;
constexpr float kInv   = 1.0f/2048.0f;
constexpr int kWihHi = 0;
constexpr int kWihLo = 24576;
constexpr int kWhhHi = 49152;
constexpr int kWhhLo = 98304;
constexpr int kSmem  = 147456;     // 147 KB -> 1 wg/CU
constexpr size_t kHPhase = 262144; // u32 elements per phase (512x512)
}

// h exchange: packed u32 (fp16 hi | lo<<16), agent-scope RELAXED atomics, in
// FRAGMENT-COALESCED layout: idx = (mi*4+sb)*8192 + kb*512 + e*64 + kg*16 + lrow
// -> reader lane l reads base + kb*512 + e*64 + l  (64 consecutive dwords per
// instruction). R16's seq-major layout made every h-load instruction span ~32
// cache lines (16 rows x 2KB apart) ~ 12k L3 txns/wg/step on the critical path.
__device__ unsigned int g_hpk[2*kHPhase];   // 2 MB
__device__ unsigned int g_flag[4096];       // 256 wgs x 16-dword stride
__device__ int          g_mode;             // is_init dtype

__device__ __forceinline__ float sigmoid_f(float v) { return 1.0f/(1.0f + __expf(-v)); }
__device__ __forceinline__ float tanh_f(float v) {
    float e = __expf(2.0f*v);
    return 1.0f - 2.0f/(e + 1.0f);
}
__device__ __forceinline__ void split2(float v, unsigned short& hi, unsigned short& lo) {
    _Float16 h = (_Float16)v;
    _Float16 l = (_Float16)((v - (float)h) * kScale);
    hi = __builtin_bit_cast(unsigned short, h);
    lo = __builtin_bit_cast(unsigned short, l);
}

__global__ void gru_prep(const unsigned int* __restrict__ is_init_raw) {
    for (int i = threadIdx.x; i < 4096; i += 256)
        __hip_atomic_store(&g_flag[i], 0u, __ATOMIC_RELAXED, __HIP_MEMORY_SCOPE_AGENT);
    if (threadIdx.x == 0) g_mode = 0;
    __syncthreads();
    unsigned m = 0;
    for (int i = threadIdx.x; i < 4096; i += 256) {
        unsigned v = is_init_raw[i];
        if (v == 0x00003F80u || v == 0x3F803F80u) m |= 4u;
        else if (v == 0x3F800000u)                m |= 2u;
        else if (v > 1u)                          m |= 1u;
    }
    if (m) atomicOr(&g_mode, (int)m);
}

// Persistent GRU. 256 wgs x 256 thr; 1 wg/CU. mi = bx&7 (8 groups x 64 rows,
// 32 wgs/group), ci = bx>>3 (32 col-blocks x 16). Split-fp16 MFMA, fp32 h.
__global__ void __launch_bounds__(256, 1)
gru_main(const float* __restrict__ x, const void* __restrict__ is_init,
         const float* __restrict__ w_ih, const float* __restrict__ w_hh,
         const float* __restrict__ b_ih, const float* __restrict__ b_hh,
         float* __restrict__ out)
{
    extern __shared__ char smem[];
    const int tid = threadIdx.x;
    const int bx  = blockIdx.x;
    const int mi  = bx & 7;
    const int ci  = bx >> 3;
    const int c0  = ci * 16;

    for (int idx = tid; idx < 3072; idx += 256) {           // w_ih: 48 x 64 float4
        int jr = idx >> 6, q = idx & 63;
        int j = (jr >> 4)*kNH + c0 + (jr & 15);
        float4 v = *(const float4*)(w_ih + (size_t)j*kNI + q*4);
        ushort4 hi, lo;
        split2(v.x, hi.x, lo.x); split2(v.y, hi.y, lo.y);
        split2(v.z, hi.z, lo.z); split2(v.w, hi.w, lo.w);
        unsigned off = ((unsigned)(jr*512 + q*8)) ^ ((unsigned)(jr & 7) << 4);
        *(ushort4*)(smem + kWihHi + off) = hi;
        *(ushort4*)(smem + kWihLo + off) = lo;
    }
    for (int idx = tid; idx < 6144; idx += 256) {           // w_hh: 48 x 128 float4
        int jr = idx >> 7, q = idx & 127;
        int j = (jr >> 4)*kNH + c0 + (jr & 15);
        float4 v = *(const float4*)(w_hh + (size_t)j*kNH + q*4);
        ushort4 hi, lo;
        split2(v.x, hi.x, lo.x); split2(v.y, hi.y, lo.y);
        split2(v.z, hi.z, lo.z); split2(v.w, hi.w, lo.w);
        unsigned off = ((unsigned)(jr*1024 + q*8)) ^ ((unsigned)(jr & 7) << 4);
        *(ushort4*)(smem + kWhhHi + off) = hi;
        *(ushort4*)(smem + kWhhLo + off) = lo;
    }
    __syncthreads();

    const int fm = g_mode;
    const int fmode = (fm & 4) ? 3 : (fm & 2) ? 2 : (fm & 1) ? 1 : 0;

    const int l    = tid & 63, w = tid >> 6;
    const int lrow = l & 15, kgrp = l >> 4;

    const int cE = c0 + lrow;
    const int mA = mi*64 + w*16 + lrow;
    const int bA = mA >> 3;
    const size_t xrow0 = ((size_t)bA*(kNS*kNA) + (mA & 7))*kNI + kgrp*8;

    const unsigned swzb = (unsigned)(lrow & 7) << 4;
    unsigned wihB[3], whhB[3];
    #pragma unroll
    for (int g = 0; g < 3; ++g) {
        wihB[g] = (unsigned)((g*16 + lrow)*512  + kgrp*16);
        whhB[g] = (unsigned)((g*16 + lrow)*1024 + kgrp*16);
    }

    const float biasR  = b_ih[cE]        + b_hh[cE];
    const float biasZ  = b_ih[kNH + cE]  + b_hh[kNH + cE];
    const float biasIN = b_ih[2*kNH + cE];
    const float biasHN = b_hh[2*kNH + cE];
    const int mE0 = mi*64 + w*16 + kgrp*4;
    const int bE  = mE0 >> 3, aE0 = mE0 & 7;

    float hreg[4] = {0.f, 0.f, 0.f, 0.f};
    float* hn_out = out + kOutElems;
    int dead = 0;
    const unsigned myFlag  = (unsigned)((mi*32 + ci)*16);
    const unsigned grpFlag = (unsigned)(mi*32)*16;

    // Exchange addressing (fragment-coalesced layout)
    const unsigned hRdBase = (unsigned)((mi*4 + w)*8192);             // + kb*512 + e*64 + l
    const unsigned hWrBase = (unsigned)((mi*4 + w)*8192
                              + ((cE >> 5) * 512) + ((cE & 7) * 64)
                              + (((cE >> 3) & 3) * 16) + kgrp*4);     // + i

#define LOADX(dh, dl, ss) do {                                                     \
        const float* xr_ = x + xrow0 + (size_t)(ss)*(kNA*kNI);                     \
        _Pragma("unroll")                                                          \
        for (int kb_ = 0; kb_ < 8; ++kb_) {                                        \
            float4 v0_ = *(const float4*)(xr_ + kb_*32);                           \
            float4 v1_ = *(const float4*)(xr_ + kb_*32 + 4);                       \
            float vv_[8] = {v0_.x,v0_.y,v0_.z,v0_.w,v1_.x,v1_.y,v1_.z,v1_.w};      \
            half8 th_, tl_;                                                        \
            _Pragma("unroll")                                                      \
            for (int e_ = 0; e_ < 8; ++e_) {                                       \
                _Float16 h_ = (_Float16)vv_[e_];                                   \
                th_[e_] = h_;                                                      \
                tl_[e_] = (_Float16)((vv_[e_] - (float)h_) * kScale);              \
            }                                                                      \
            dh[kb_] = th_; dl[kb_] = tl_;                                          \
        }                                                                          \
    } while (0)

    half8 xfh[8], xfl[8], xnh[8], xnl[8];
    LOADX(xfh, xfl, 0);

    for (int s = 0; s < kNS; ++s) {
        const int ii = bA*kNS + s;
        const int ie = bE*kNS + s;
        int iniA, iniE;
        switch (fmode) {
            case 3:  iniA = ((const unsigned short*)is_init)[ii] != 0;
                     iniE = ((const unsigned short*)is_init)[ie] != 0; break;
            case 2:  iniA = ((const float*)is_init)[ii] != 0.f;
                     iniE = ((const float*)is_init)[ie] != 0.f;       break;
            case 1:  iniA = ((const unsigned char*)is_init)[ii] != 0;
                     iniE = ((const unsigned char*)is_init)[ie] != 0; break;
            default: iniA = ((const int*)is_init)[ii] != 0;
                     iniE = ((const int*)is_init)[ie] != 0;           break;
        }
        f32x4 aR = {0,0,0,0}, aZ = {0,0,0,0}, aGN = {0,0,0,0}, aHN = {0,0,0,0};
        f32x4 lR = {0,0,0,0}, lZ = {0,0,0,0}, lGN = {0,0,0,0}, lHN = {0,0,0,0};

        // ---- gi (independent of h; runs before the wait) ----
        #pragma unroll
        for (int kb = 0; kb < 8; ++kb) {
            {   half8 bhi = *(const half8*)(smem + kWihHi + ((wihB[0] + kb*64) ^ swzb));
                half8 blo = *(const half8*)(smem + kWihLo + ((wihB[0] + kb*64) ^ swzb));
                aR = MFMA_F16(xfh[kb], bhi, aR);
                lR = MFMA_F16(xfl[kb], bhi, lR);
                lR = MFMA_F16(xfh[kb], blo, lR); }
            {   half8 bhi = *(const half8*)(smem + kWihHi + ((wihB[1] + kb*64) ^ swzb));
                half8 blo = *(const half8*)(smem + kWihLo + ((wihB[1] + kb*64) ^ swzb));
                aZ = MFMA_F16(xfh[kb], bhi, aZ);
                lZ = MFMA_F16(xfl[kb], bhi, lZ);
                lZ = MFMA_F16(xfh[kb], blo, lZ); }
            {   half8 bhi = *(const half8*)(smem + kWihHi + ((wihB[2] + kb*64) ^ swzb));
                half8 blo = *(const half8*)(smem + kWihLo + ((wihB[2] + kb*64) ^ swzb));
                aGN = MFMA_F16(xfh[kb], bhi, aGN);
                lGN = MFMA_F16(xfl[kb], bhi, lGN);
                lGN = MFMA_F16(xfh[kb], blo, lGN); }
        }

        if (s + 1 < kNS) LOADX(xnh, xnl, s + 1);

        // ---- wait for h(s): 32 lanes poll 32 producer flags in parallel ----
        if (s > 0) {
            if (tid < 32 && !dead) {
                const unsigned target = (unsigned)s;
                long it = 0;
                while (__hip_atomic_load(&g_flag[grpFlag + tid*16], __ATOMIC_RELAXED,
                                         __HIP_MEMORY_SCOPE_AGENT) < target) {
                    if (++it > 50000000L) { dead = 1; break; }
                    __builtin_amdgcn_s_sleep(1);
                }
            }
            __syncthreads();
            const unsigned int* hp = g_hpk + (size_t)(s & 1)*kHPhase + hRdBase;
            const half8 zz = {};
            #pragma unroll
            for (int kb = 0; kb < 16; ++kb) {
                unsigned wv[8];
                #pragma unroll
                for (int e = 0; e < 8; ++e)     // 64 consecutive dwords per (kb,e)
                    wv[e] = __hip_atomic_load(hp + kb*512 + e*64 + l, __ATOMIC_RELAXED,
                                              __HIP_MEMORY_SCOPE_AGENT);
                uint4v ph, pl;
                ph[0] = (wv[0]&0xFFFFu)|(wv[1]<<16); pl[0] = (wv[0]>>16)|(wv[1]&0xFFFF0000u);
                ph[1] = (wv[2]&0xFFFFu)|(wv[3]<<16); pl[1] = (wv[2]>>16)|(wv[3]&0xFFFF0000u);
                ph[2] = (wv[4]&0xFFFFu)|(wv[5]<<16); pl[2] = (wv[4]>>16)|(wv[5]&0xFFFF0000u);
                ph[3] = (wv[6]&0xFFFFu)|(wv[7]<<16); pl[3] = (wv[6]>>16)|(wv[7]&0xFFFF0000u);
                half8 ahi = __builtin_bit_cast(half8, ph);
                half8 alo = __builtin_bit_cast(half8, pl);
                ahi = iniA ? zz : ahi;
                alo = iniA ? zz : alo;
                {   half8 bhi = *(const half8*)(smem + kWhhHi + ((whhB[0] + kb*64) ^ swzb));
                    half8 blo = *(const half8*)(smem + kWhhLo + ((whhB[0] + kb*64) ^ swzb));
                    aR = MFMA_F16(ahi, bhi, aR);
                    lR = MFMA_F16(alo, bhi, lR);
                    lR = MFMA_F16(ahi, blo, lR); }
                {   half8 bhi = *(const half8*)(smem + kWhhHi + ((whhB[1] + kb*64) ^ swzb));
                    half8 blo = *(const half8*)(smem + kWhhLo + ((whhB[1] + kb*64) ^ swzb));
                    aZ = MFMA_F16(ahi, bhi, aZ);
                    lZ = MFMA_F16(alo, bhi, lZ);
                    lZ = MFMA_F16(ahi, blo, lZ); }
                {   half8 bhi = *(const half8*)(smem + kWhhHi + ((whhB[2] + kb*64) ^ swzb));
                    half8 blo = *(const half8*)(smem + kWhhLo + ((whhB[2] + kb*64) ^ swzb));
                    aHN = MFMA_F16(ahi, bhi, aHN);
                    lHN = MFMA_F16(alo, bhi, lHN);
                    lHN = MFMA_F16(ahi, blo, lHN); }
            }
        }

        // ---- gates + h update; h stores (4 consecutive dwords/lane) FIRST ----
        unsigned int* hop = g_hpk + (size_t)((s+1) & 1)*kHPhase;
        float hvout[4];
        #pragma unroll
        for (int i = 0; i < 4; ++i) {
            float pr  = aR[i]  + lR[i]*kInv  + biasR;
            float pz  = aZ[i]  + lZ[i]*kInv  + biasZ;
            float gin = aGN[i] + lGN[i]*kInv + biasIN;
            float ghn = aHN[i] + lHN[i]*kInv + biasHN;
            float htv = iniE ? 0.f : hreg[i];
            float r  = sigmoid_f(pr);
            float zg = sigmoid_f(pz);
            float nn = tanh_f(gin + r*ghn);
            float hv = (1.f - zg)*nn + zg*htv;
            hreg[i] = hv; hvout[i] = hv;
            unsigned short shi, slo;
            split2(hv, shi, slo);
            unsigned int pk = (unsigned)shi | ((unsigned)slo << 16);
            __hip_atomic_store(&hop[hWrBase + (unsigned)i], pk,
                               __ATOMIC_RELAXED, __HIP_MEMORY_SCOPE_AGENT);
        }

        // ---- publish h(s+1): per-wg step-stamp flag (plain store) ----
        if (s < kNS-1) {
            __syncthreads();   // per-wave vmcnt(0): h stores acked at L3
            if (tid == 0)
                __hip_atomic_store(&g_flag[myFlag], (unsigned)(s+1),
                                   __ATOMIC_RELAXED, __HIP_MEMORY_SCOPE_AGENT);
        }

        // ---- out stores off the critical path ----
        const size_t obase = ((size_t)bE*(kNS*kNA) + (size_t)s*kNA + aE0)*kNH + cE;
        #pragma unroll
        for (int i = 0; i < 4; ++i)
            out[obase + (size_t)i*kNH] = hvout[i];
        if (s == kNS-1) {
            #pragma unroll
            for (int i = 0; i < 4; ++i)
                hn_out[(size_t)(mE0 + i)*kNH + cE] = hreg[i];
        }

        if (s < kNS-1) {
            #pragma unroll
            for (int i = 0; i < 8; ++i) { xfh[i] = xnh[i]; xfl[i] = xnl[i]; }
        }
    }
#undef LOADX
}

extern "C" void kernel_launch(void* const* d_in, const int* in_sizes, int n_in,
                              void* d_out, int out_size, void* d_ws, size_t ws_size,
                              hipStream_t stream) {
    const int want[6] = {33554432, 16384, 393216, 786432, 1536, 1536};
    const void* res[6] = {nullptr, nullptr, nullptr, nullptr, nullptr, nullptr};
    bool used[64] = {false};
    for (int k = 0; k < 6; ++k)
        for (int i = 0; i < n_in && i < 64; ++i)
            if (!used[i] && in_sizes[i] == want[k]) { res[k] = d_in[i]; used[i] = true; break; }
    bool ok = true;
    for (int k = 0; k < 6; ++k) if (!res[k]) ok = false;
    if (!ok) for (int k = 0; k < 6; ++k) res[k] = d_in[k];

    const float* x       = (const float*)res[0];
    const void*  is_init = res[1];
    const float* w_ih    = (const float*)res[2];
    const float* w_hh    = (const float*)res[3];
    const float* b_ih    = (const float*)res[4];
    const float* b_hh    = (const float*)res[5];
    float* out = (float*)d_out;

    gru_prep<<<1, 256, 0, stream>>>((const unsigned int*)is_init);

    hipFuncSetAttribute((const void*)gru_main,
                        hipFuncAttributeMaxDynamicSharedMemorySize, kSmem);
    gru_main<<<256, 256, kSmem, stream>>>(x, is_init, w_ih, w_hh, b_ih, b_hh, out);
}